// Round 3
// baseline (4588.750 us; speedup 1.0000x reference)
//
#include <hip/hip_runtime.h>

// CrossModalHyperedgeInteraction: 3-modality cross-attention, MI355X bf16-MFMA impl.
// R2: attn_k rewritten — zero-LDS, zero-barrier, swapped-QK^T with permuted key rows so
// the P handoff is lane-local (no LDS stash, no shuffles). proj_k unchanged.
// D=512, B=32, K={1024,768,512}, tokOff={0,32768,57344}, total tokens 73728.

typedef unsigned short u16;
typedef unsigned int   u32;
typedef __attribute__((ext_vector_type(8))) short vbf8;   // 8 bf16 (4 VGPR) MFMA A/B frag
typedef __attribute__((ext_vector_type(4))) float vf4;    // MFMA C/D frag

#define MFMA(a,b,c) __builtin_amdgcn_mfma_f32_16x16x32_bf16(a,b,c,0,0,0)

__device__ __forceinline__ u16 f2bf(float f){
  u32 x = __float_as_uint(f);
  return (u16)((x + 0x7fffu + ((x >> 16) & 1u)) >> 16);   // RNE bf16
}

// ---------------- kernel 1: W fp32 -> bf16 (4 weights, 512x512 each) ----------------
__global__ void wconv_k(const float* __restrict__ Wq, const float* __restrict__ Wk,
                        const float* __restrict__ Wv, const float* __restrict__ Wo,
                        u16* __restrict__ Wbf){
  int i = blockIdx.x * 256 + threadIdx.x;            // 0..262143, 4 floats each
  int w = i >> 16;
  int off = (i & 65535) << 2;
  const float* src = (w == 0) ? Wq : (w == 1) ? Wk : (w == 2) ? Wv : Wo;
  float4 v = *(const float4*)(src + off);
  u32 lo = (u32)f2bf(v.x) | ((u32)f2bf(v.y) << 16);
  u32 hi = (u32)f2bf(v.z) | ((u32)f2bf(v.w) << 16);
  uint2 p; p.x = lo; p.y = hi;
  *(uint2*)(Wbf + (w << 18) + off) = p;
}

// ---------------- kernel 2: projections C = E*W^T + b ----------------
// grid (512, 4 weights, 3 modalities), block 256 (4 waves, 16 rows each, 512 cols).
// z-outputs: widx 0->Qb (scaled 1/sqrt(512)), 1->Kb, 2->Vt (transposed), 3->Oproj fp32 in d_out.
__global__ void __launch_bounds__(256) proj_k(
    const float* __restrict__ E0, const float* __restrict__ E1, const float* __restrict__ E2,
    const u16* __restrict__ Wbf,
    const float* __restrict__ bq, const float* __restrict__ bk,
    const float* __restrict__ bv, const float* __restrict__ bo,
    u16* __restrict__ Qb, u16* __restrict__ Kb, u16* __restrict__ Vtb,
    float* __restrict__ outF)
{
  const int mod = blockIdx.z, widx = blockIdx.y, xt = blockIdx.x;
  const int Km   = (mod == 0) ? 1024 : (mod == 1) ? 768 : 512;
  const int Mmod = Km * 32;
  if (xt * 64 >= Mmod) return;
  const int tokOff = (mod == 0) ? 0 : (mod == 1) ? 32768 : 57344;
  const float* E = (mod == 0) ? E0 : (mod == 1) ? E1 : E2;
  const u16* W = Wbf + (widx << 18);
  const float* bias = (widx == 0) ? bq : (widx == 1) ? bk : (widx == 2) ? bv : bo;

  __shared__ __align__(16) char smem[36864];   // Elds [64][32] @0 (4KB) | Wlds [512][32] @4096 (32KB)

  const int tid = threadIdx.x;
  const int wv = tid >> 6, l = tid & 63, g = l >> 4, c = l & 15;

  vf4 acc[32];
  #pragma unroll
  for (int ch = 0; ch < 32; ++ch) acc[ch] = (vf4){0.f, 0.f, 0.f, 0.f};

  for (int kt = 0; kt < 16; ++kt){
    { // stage E tile (convert fp32->bf16): 64 rows x 4 slots of 16B
      int row = tid >> 2, sl = tid & 3;
      const float* s = E + (size_t)(xt * 64 + row) * 512 + kt * 32 + sl * 8;
      float4 aa = *(const float4*)s;
      float4 bb = *(const float4*)(s + 4);
      int4 p;
      p.x = (int)((u32)f2bf(aa.x) | ((u32)f2bf(aa.y) << 16));
      p.y = (int)((u32)f2bf(aa.z) | ((u32)f2bf(aa.w) << 16));
      p.z = (int)((u32)f2bf(bb.x) | ((u32)f2bf(bb.y) << 16));
      p.w = (int)((u32)f2bf(bb.z) | ((u32)f2bf(bb.w) << 16));
      *(int4*)(smem + row * 64 + ((sl * 16) ^ ((row & 3) << 4))) = p;
    }
    // stage W tile: 512 rows x 4 slots of 16B (already bf16)
    #pragma unroll
    for (int it = 0; it < 8; ++it){
      int flat = it * 256 + tid;
      int row = flat >> 2, sl = flat & 3;
      int4 v = *(const int4*)(W + row * 512 + kt * 32 + sl * 8);
      *(int4*)(smem + 4096 + row * 64 + ((sl * 16) ^ ((row & 3) << 4))) = v;
    }
    __syncthreads();
    const int arow = wv * 16 + c;
    vbf8 af = *(const vbf8*)(smem + arow * 64 + ((g * 16) ^ ((arow & 3) << 4)));
    #pragma unroll
    for (int ch = 0; ch < 32; ++ch){
      int e = ch * 16 + c;
      vbf8 bf = *(const vbf8*)(smem + 4096 + e * 64 + ((g * 16) ^ ((e & 3) << 4)));
      acc[ch] = MFMA(af, bf, acc[ch]);
    }
    __syncthreads();
  }

  const float scale = (widx == 0) ? 0.04419417382415922f : 1.0f;   // 1/sqrt(512) folded into Q

  if (widx == 2){
    // V: write transposed Vt[mod][b][e=512][Km] via LDS transpose (stride-65 pad)
    const int b = (xt * 64) / Km, tokl = (xt * 64) % Km;
    u16* T = (u16*)smem;                                   // [256 e][65]
    const size_t vbase = (size_t)tokOff * 512 + (size_t)b * 512 * Km + tokl;
    for (int h = 0; h < 2; ++h){
      __syncthreads();
      #pragma unroll
      for (int ch = 0; ch < 16; ++ch){
        int chg = h * 16 + ch;
        int el = ch * 16 + c;                              // e - h*256
        float bv_ = bias[h * 256 + el];
        #pragma unroll
        for (int r = 0; r < 4; ++r){
          int tk = wv * 16 + g * 4 + r;
          T[el * 65 + tk] = f2bf(acc[chg][r] + bv_);
        }
      }
      __syncthreads();
      #pragma unroll
      for (int it = 0; it < 8; ++it){
        int flat = it * 256 + tid;
        int el = flat >> 3, tg = flat & 7;
        u16 a0 = T[el*65 + tg*8 + 0], a1 = T[el*65 + tg*8 + 1];
        u16 a2 = T[el*65 + tg*8 + 2], a3 = T[el*65 + tg*8 + 3];
        u16 a4 = T[el*65 + tg*8 + 4], a5 = T[el*65 + tg*8 + 5];
        u16 a6 = T[el*65 + tg*8 + 6], a7 = T[el*65 + tg*8 + 7];
        int4 p;
        p.x = (int)((u32)a0 | ((u32)a1 << 16));
        p.y = (int)((u32)a2 | ((u32)a3 << 16));
        p.z = (int)((u32)a4 | ((u32)a5 << 16));
        p.w = (int)((u32)a6 | ((u32)a7 << 16));
        *(int4*)(Vtb + vbase + (size_t)(h * 256 + el) * Km + tg * 8) = p;
      }
    }
  } else {
    #pragma unroll
    for (int ch = 0; ch < 32; ++ch){
      int col = ch * 16 + c;
      float bv_ = bias[col];
      #pragma unroll
      for (int r = 0; r < 4; ++r){
        int tok = xt * 64 + wv * 16 + g * 4 + r;
        float val = (acc[ch][r] + bv_) * scale;
        size_t idx = (size_t)(tokOff + tok) * 512 + col;
        if (widx == 3)      outF[idx] = val;            // Oproj fp32 (relu later)
        else if (widx == 0) Qb[idx] = f2bf(val);        // Q pre-scaled
        else                Kb[idx] = f2bf(val);
      }
    }
  }
}

// ---------------- kernel 3: cross attention (zero-LDS, zero-barrier) ----------------
// grid (16, 32 batch, 3 modality), block 256 = 4 independent waves, each wave 16 q-rows.
// Swapped QK^T: A = K (16 of 32 keys, PERMUTED rows m0(c)=(c>>2)*8+(c&3)), B = Q.
//   MFMA0 covers keys {8g..8g+3}, MFMA1 keys {8g+4..8g+7}  (g = lane>>4).
//   => lane (g,c) holds exactly keys [8g..8g+7] of S^T[.][q=c] in regs — the PV B-frag
//      (K=32 contraction) is a lane-local pack of exp() values. No LDS, no shuffles.
// PV: A = Vt rows (d), B = packed P. acc[ch] lane (g,c) reg r = out[d=ch*16+g*4+r][q=c].
// srcI==0: d_out += msg1 (Oproj already there). srcI==1: d_out = relu(d_out + msg2).
__global__ void __launch_bounds__(256) attn_k(
    const u16* __restrict__ Qb, const u16* __restrict__ Kb,
    const u16* __restrict__ Vtb, float* __restrict__ outF)
{
  const int m = blockIdx.z, y = blockIdx.y, xt = blockIdx.x;
  const int Km = (m == 0) ? 1024 : (m == 1) ? 768 : 512;
  if (xt * 64 >= Km) return;
  const int tokOffM = (m == 0) ? 0 : (m == 1) ? 32768 : 57344;

  const int tid = threadIdx.x, wv = tid >> 6, l = tid & 63, g = l >> 4, c = l & 15;
  const int qbase = tokOffM + y * Km + xt * 64 + wv * 16;  // global row of wave's first q
  const int kperm = (c >> 2) * 8 + (c & 3);                // A-row -> key permutation (MFMA0)

  // Q fragments (B operand): qf[ch] elem j = Q[q=c][d=ch*32+g*8+j]
  vbf8 qf[16];
  {
    const u16* qp = Qb + (size_t)(qbase + c) * 512 + g * 8;
    #pragma unroll
    for (int ch = 0; ch < 16; ++ch) qf[ch] = *(const vbf8*)(qp + ch * 32);
  }

  vf4 acc[32];
  #pragma unroll
  for (int ch = 0; ch < 32; ++ch) acc[ch] = (vf4){0.f, 0.f, 0.f, 0.f};
  float lp = 0.f;

  for (int srcI = 0; srcI < 2; ++srcI){
    const int n = (srcI == 0) ? ((m == 0) ? 1 : 0) : ((m == 2) ? 1 : 2);
    const int Kn = (n == 0) ? 1024 : (n == 1) ? 768 : 512;
    const int tokOffN = (n == 0) ? 0 : (n == 1) ? 32768 : 57344;
    const size_t kRow0 = (size_t)(tokOffN + y * Kn);
    const size_t vBase = (size_t)tokOffN * 512 + (size_t)y * 512 * Kn;

    for (int kt = 0; kt < Kn / 32; ++kt){
      // ---- QK^T (swapped): S^T[key][q] for this wave's 16 q-rows, 32 keys ----
      const u16* kp0 = Kb + (kRow0 + kt * 32 + kperm) * 512 + g * 8;       // keys {8g..8g+3}
      const u16* kp1 = kp0 + 4 * 512;                                      // keys {8g+4..8g+7}
      vf4 s0 = (vf4){0.f,0.f,0.f,0.f}, s1 = (vf4){0.f,0.f,0.f,0.f};
      #pragma unroll
      for (int ch = 0; ch < 16; ++ch){
        vbf8 ka = *(const vbf8*)(kp0 + ch * 32);
        vbf8 kb = *(const vbf8*)(kp1 + ch * 32);
        s0 = MFMA(ka, qf[ch], s0);
        s1 = MFMA(kb, qf[ch], s1);
      }
      // ---- exp + lane-local pack into PV B-frag (keys 8g..8g+7 for q=c) ----
      float e00 = __expf(s0[0]), e01 = __expf(s0[1]), e02 = __expf(s0[2]), e03 = __expf(s0[3]);
      float e10 = __expf(s1[0]), e11 = __expf(s1[1]), e12 = __expf(s1[2]), e13 = __expf(s1[3]);
      lp += (e00 + e01 + e02 + e03) + (e10 + e11 + e12 + e13);
      vbf8 pb;
      pb[0] = (short)f2bf(e00); pb[1] = (short)f2bf(e01);
      pb[2] = (short)f2bf(e02); pb[3] = (short)f2bf(e03);
      pb[4] = (short)f2bf(e10); pb[5] = (short)f2bf(e11);
      pb[6] = (short)f2bf(e12); pb[7] = (short)f2bf(e13);
      // ---- PV: acc[d-chunk] += Vt-frag * P-frag  (K=32 over this kt's keys) ----
      const u16* vp = Vtb + vBase + (size_t)c * Kn + kt * 32 + g * 8;
      #pragma unroll
      for (int ch = 0; ch < 32; ++ch){
        vbf8 va = *(const vbf8*)(vp + (size_t)(ch * 16) * Kn);
        acc[ch] = MFMA(va, pb, acc[ch]);
      }
    }
    // ---- finalize source: softmax denominator (sum over the 4 g-groups) ----
    float t = lp;
    t += __shfl_xor(t, 16);
    t += __shfl_xor(t, 32);
    const float w = 1.0f / t;
    lp = 0.f;
    // merge into d_out: lane (g,c) owns out[q=qbase+c][d=ch*16+g*4 .. +3]
    float* op = outF + (size_t)(qbase + c) * 512 + g * 4;
    #pragma unroll
    for (int ch = 0; ch < 32; ++ch){
      float4* p4 = (float4*)(op + ch * 16);
      float4 v = *p4;
      v.x += acc[ch][0] * w; v.y += acc[ch][1] * w;
      v.z += acc[ch][2] * w; v.w += acc[ch][3] * w;
      if (srcI == 1){
        v.x = fmaxf(v.x, 0.f); v.y = fmaxf(v.y, 0.f);
        v.z = fmaxf(v.z, 0.f); v.w = fmaxf(v.w, 0.f);
      }
      *p4 = v;
      acc[ch] = (vf4){0.f, 0.f, 0.f, 0.f};
    }
  }
}

// ---------------- host launcher ----------------
extern "C" void kernel_launch(void* const* d_in, const int* in_sizes, int n_in,
                              void* d_out, int out_size, void* d_ws, size_t ws_size,
                              hipStream_t stream){
  const float* E0 = (const float*)d_in[0];
  const float* E1 = (const float*)d_in[1];
  const float* E2 = (const float*)d_in[2];
  const float* Wq = (const float*)d_in[3];
  const float* bq = (const float*)d_in[4];
  const float* Wk = (const float*)d_in[5];
  const float* bk = (const float*)d_in[6];
  const float* Wv = (const float*)d_in[7];
  const float* bv = (const float*)d_in[8];
  const float* Wo = (const float*)d_in[9];
  const float* bo = (const float*)d_in[10];
  float* outF = (float*)d_out;

  char* ws = (char*)d_ws;
  const size_t SZ = 75497472u;                 // 73728*512*2 bytes (bf16)
  u16* Wbf = (u16*)ws;                         // 2 MB
  u16* Qb  = (u16*)(ws + (size_t)(2u << 20));
  u16* Kb  = (u16*)(ws + (size_t)(2u << 20) + SZ);
  u16* Vtb = (u16*)(ws + (size_t)(2u << 20) + 2 * SZ);
  // requires ws_size >= 2MB + 3*72MB = ~228.6MB

  wconv_k<<<dim3(1024), dim3(256), 0, stream>>>(Wq, Wk, Wv, Wo, Wbf);
  proj_k<<<dim3(512, 4, 3), dim3(256), 0, stream>>>(E0, E1, E2, Wbf, bq, bk, bv, bo,
                                                    Qb, Kb, Vtb, outF);
  attn_k<<<dim3(16, 32, 3), dim3(256), 0, stream>>>(Qb, Kb, Vtb, outF);
}

// Round 5
// 1144.928 us; speedup vs baseline: 4.0079x; 4.0079x over previous
//
#include <hip/hip_runtime.h>

// CrossModalHyperedgeInteraction: 3-modality cross-attention, MI355X bf16-MFMA impl.
// R5 = R4 resubmit (infra failure, no signal): attn_k = LDS double-buffered async pipeline
// (global_load_lds + counted vmcnt + raw barriers), lane-local P handoff (swapped QK^T,
// permuted keys), swizzled conflict-free LDS, q-tile 128 (8 waves), XCD-chunked swizzle.
// D=512, B=32, K={1024,768,512}, tokOff={0,32768,57344}, total tokens 73728.

typedef unsigned short u16;
typedef unsigned int   u32;
typedef __attribute__((ext_vector_type(8))) short vbf8;   // 8 bf16 (4 VGPR) MFMA A/B frag
typedef __attribute__((ext_vector_type(4))) float vf4;    // MFMA C/D frag

#define MFMA(a,b,c) __builtin_amdgcn_mfma_f32_16x16x32_bf16(a,b,c,0,0,0)

__device__ __forceinline__ u16 f2bf(float f){
  u32 x = __float_as_uint(f);
  return (u16)((x + 0x7fffu + ((x >> 16) & 1u)) >> 16);   // RNE bf16
}

__device__ __forceinline__ void gll16(const void* g, void* l){
  __builtin_amdgcn_global_load_lds(
      (const __attribute__((address_space(1))) u32*)g,
      (__attribute__((address_space(3))) u32*)l, 16, 0, 0);
}

// ---------------- kernel 1: W fp32 -> bf16 (4 weights, 512x512 each) ----------------
__global__ void wconv_k(const float* __restrict__ Wq, const float* __restrict__ Wk,
                        const float* __restrict__ Wv, const float* __restrict__ Wo,
                        u16* __restrict__ Wbf){
  int i = blockIdx.x * 256 + threadIdx.x;            // 0..262143, 4 floats each
  int w = i >> 16;
  int off = (i & 65535) << 2;
  const float* src = (w == 0) ? Wq : (w == 1) ? Wk : (w == 2) ? Wv : Wo;
  float4 v = *(const float4*)(src + off);
  u32 lo = (u32)f2bf(v.x) | ((u32)f2bf(v.y) << 16);
  u32 hi = (u32)f2bf(v.z) | ((u32)f2bf(v.w) << 16);
  uint2 p; p.x = lo; p.y = hi;
  *(uint2*)(Wbf + (w << 18) + off) = p;
}

// ---------------- kernel 2: projections C = E*W^T + b (unchanged from R2) ----------------
__global__ void __launch_bounds__(256) proj_k(
    const float* __restrict__ E0, const float* __restrict__ E1, const float* __restrict__ E2,
    const u16* __restrict__ Wbf,
    const float* __restrict__ bq, const float* __restrict__ bk,
    const float* __restrict__ bv, const float* __restrict__ bo,
    u16* __restrict__ Qb, u16* __restrict__ Kb, u16* __restrict__ Vtb,
    float* __restrict__ outF)
{
  const int mod = blockIdx.z, widx = blockIdx.y, xt = blockIdx.x;
  const int Km   = (mod == 0) ? 1024 : (mod == 1) ? 768 : 512;
  const int Mmod = Km * 32;
  if (xt * 64 >= Mmod) return;
  const int tokOff = (mod == 0) ? 0 : (mod == 1) ? 32768 : 57344;
  const float* E = (mod == 0) ? E0 : (mod == 1) ? E1 : E2;
  const u16* W = Wbf + (widx << 18);
  const float* bias = (widx == 0) ? bq : (widx == 1) ? bk : (widx == 2) ? bv : bo;

  __shared__ __align__(16) char smem[36864];   // Elds [64][32] @0 | Wlds [512][32] @4096

  const int tid = threadIdx.x;
  const int wv = tid >> 6, l = tid & 63, g = l >> 4, c = l & 15;

  vf4 acc[32];
  #pragma unroll
  for (int ch = 0; ch < 32; ++ch) acc[ch] = (vf4){0.f, 0.f, 0.f, 0.f};

  for (int kt = 0; kt < 16; ++kt){
    { // stage E tile (convert fp32->bf16)
      int row = tid >> 2, sl = tid & 3;
      const float* s = E + (size_t)(xt * 64 + row) * 512 + kt * 32 + sl * 8;
      float4 aa = *(const float4*)s;
      float4 bb = *(const float4*)(s + 4);
      int4 p;
      p.x = (int)((u32)f2bf(aa.x) | ((u32)f2bf(aa.y) << 16));
      p.y = (int)((u32)f2bf(aa.z) | ((u32)f2bf(aa.w) << 16));
      p.z = (int)((u32)f2bf(bb.x) | ((u32)f2bf(bb.y) << 16));
      p.w = (int)((u32)f2bf(bb.z) | ((u32)f2bf(bb.w) << 16));
      *(int4*)(smem + row * 64 + ((sl * 16) ^ ((row & 3) << 4))) = p;
    }
    #pragma unroll
    for (int it = 0; it < 8; ++it){
      int flat = it * 256 + tid;
      int row = flat >> 2, sl = flat & 3;
      int4 v = *(const int4*)(W + row * 512 + kt * 32 + sl * 8);
      *(int4*)(smem + 4096 + row * 64 + ((sl * 16) ^ ((row & 3) << 4))) = v;
    }
    __syncthreads();
    const int arow = wv * 16 + c;
    vbf8 af = *(const vbf8*)(smem + arow * 64 + ((g * 16) ^ ((arow & 3) << 4)));
    #pragma unroll
    for (int ch = 0; ch < 32; ++ch){
      int e = ch * 16 + c;
      vbf8 bf = *(const vbf8*)(smem + 4096 + e * 64 + ((g * 16) ^ ((e & 3) << 4)));
      acc[ch] = MFMA(af, bf, acc[ch]);
    }
    __syncthreads();
  }

  const float scale = (widx == 0) ? 0.04419417382415922f : 1.0f;

  if (widx == 2){
    const int b = (xt * 64) / Km, tokl = (xt * 64) % Km;
    u16* T = (u16*)smem;                                   // [256 e][65]
    const size_t vbase = (size_t)tokOff * 512 + (size_t)b * 512 * Km + tokl;
    for (int h = 0; h < 2; ++h){
      __syncthreads();
      #pragma unroll
      for (int ch = 0; ch < 16; ++ch){
        int chg = h * 16 + ch;
        int el = ch * 16 + c;
        float bv_ = bias[h * 256 + el];
        #pragma unroll
        for (int r = 0; r < 4; ++r){
          int tk = wv * 16 + g * 4 + r;
          T[el * 65 + tk] = f2bf(acc[chg][r] + bv_);
        }
      }
      __syncthreads();
      #pragma unroll
      for (int it = 0; it < 8; ++it){
        int flat = it * 256 + tid;
        int el = flat >> 3, tg = flat & 7;
        u16 a0 = T[el*65 + tg*8 + 0], a1 = T[el*65 + tg*8 + 1];
        u16 a2 = T[el*65 + tg*8 + 2], a3 = T[el*65 + tg*8 + 3];
        u16 a4 = T[el*65 + tg*8 + 4], a5 = T[el*65 + tg*8 + 5];
        u16 a6 = T[el*65 + tg*8 + 6], a7 = T[el*65 + tg*8 + 7];
        int4 p;
        p.x = (int)((u32)a0 | ((u32)a1 << 16));
        p.y = (int)((u32)a2 | ((u32)a3 << 16));
        p.z = (int)((u32)a4 | ((u32)a5 << 16));
        p.w = (int)((u32)a6 | ((u32)a7 << 16));
        *(int4*)(Vtb + vbase + (size_t)(h * 256 + el) * Km + tg * 8) = p;
      }
    }
  } else {
    #pragma unroll
    for (int ch = 0; ch < 32; ++ch){
      int col = ch * 16 + c;
      float bv_ = bias[col];
      #pragma unroll
      for (int r = 0; r < 4; ++r){
        int tok = xt * 64 + wv * 16 + g * 4 + r;
        float val = (acc[ch][r] + bv_) * scale;
        size_t idx = (size_t)(tokOff + tok) * 512 + col;
        if (widx == 3)      outF[idx] = val;
        else if (widx == 0) Qb[idx] = f2bf(val);
        else                Kb[idx] = f2bf(val);
      }
    }
  }
}

// ---------------- kernel 3: cross attention (async dbuf LDS pipeline) ----------------
// 576 blocks x 512 thr (8 waves, 16 q-rows each). Per 32-key tile: prefetch next tile via
// global_load_lds (8/wave), s_waitcnt vmcnt(8) (counted), raw s_barrier; QK^T swapped
// (A=K perm rows -> lane-local P), PV from swizzled Vt tile. 2 barriers/tile, 0 conflicts.
__global__ void __launch_bounds__(512, 2) attn_k(
    const u16* __restrict__ Qb, const u16* __restrict__ Kb,
    const u16* __restrict__ Vtb, float* __restrict__ outF)
{
  __shared__ __align__(16) char smem[131072];  // K dbuf 2x32KB @0 | Vt dbuf 2x32KB @65536

  // XCD-chunked swizzle: 576 = 8 XCD * 72 contiguous (m,y) groups
  const int lin = blockIdx.x;
  const int swz = (lin & 7) * 72 + (lin >> 3);
  int m, y, xq;
  if (swz < 256)      { m = 0; y = swz >> 3; xq = swz & 7; }
  else if (swz < 448) { int r = swz - 256; m = 1; y = r / 6; xq = r - y * 6; }
  else                { int r = swz - 448; m = 2; y = r >> 2; xq = r & 3; }

  const int Km = (m == 0) ? 1024 : (m == 1) ? 768 : 512;
  const int tokOffM = (m == 0) ? 0 : (m == 1) ? 32768 : 57344;

  const int tid = threadIdx.x, wv = tid >> 6, l = tid & 63, g = l >> 4, c = l & 15;
  const int qbase = tokOffM + y * Km + xq * 128 + wv * 16;

  const int kperm = (c >> 2) * 8 + (c & 3);        // A-row -> key permutation (sel 0)
  const int chx   = c >> 2;                        // K-read slot XOR (high bits of F)
  const int kb_lane = kperm * 1024 + ((g ^ (c & 3)) << 4);
  const int vb_lane = c * 64 + ((g ^ ((c >> 1) & 3)) << 4);

  // Q fragments: qf[ch] elem j = Q[q=qbase+c][d=ch*32+g*8+j]
  vbf8 qf[16];
  {
    const u16* qp = Qb + (size_t)(qbase + c) * 512 + g * 8;
    #pragma unroll
    for (int ch = 0; ch < 16; ++ch) qf[ch] = *(const vbf8*)(qp + ch * 32);
  }

  vf4 acc[32];
  #pragma unroll
  for (int ch = 0; ch < 32; ++ch) acc[ch] = (vf4){0.f, 0.f, 0.f, 0.f};
  float lp = 0.f;

  for (int srcI = 0; srcI < 2; ++srcI){
    const int n = (srcI == 0) ? ((m == 0) ? 1 : 0) : ((m == 2) ? 1 : 2);
    const int Kn = (n == 0) ? 1024 : (n == 1) ? 768 : 512;
    const int NT = Kn >> 5;
    const int tokOffN = (n == 0) ? 0 : (n == 1) ? 32768 : 57344;
    const size_t kRow0 = (size_t)(tokOffN + y * Kn);
    const size_t vBase = (size_t)tokOffN * 512 + (size_t)y * 512 * Kn;

    auto stage = [&](int kt, int buf){
      char* kd = smem + buf * 32768;
      char* vd = smem + 65536 + buf * 32768;
      const size_t kB = (kRow0 + kt * 32) * 512;
      #pragma unroll
      for (int p = 0; p < 4; ++p){                  // K tile: linear LDS, pre-swizzled src
        int t = p * 512 + tid;
        int key = t >> 6, sl = t & 63;
        int F = (key & 3) | (((key >> 3) & 3) << 2);
        gll16(Kb + kB + (size_t)key * 512 + ((sl ^ F) << 3), kd + t * 16);
      }
      #pragma unroll
      for (int p = 0; p < 4; ++p){                  // Vt tile
        int t = p * 512 + tid;
        int d = t >> 2, ks = t & 3;
        gll16(Vtb + vBase + (size_t)d * Kn + kt * 32 + ((ks ^ ((d >> 1) & 3)) << 3),
              vd + t * 16);
      }
    };

    stage(0, 0);
    for (int kt = 0; kt < NT; ++kt){
      const int cur = kt & 1;
      if (kt + 1 < NT){
        stage(kt + 1, cur ^ 1);                     // prefetch stays in flight
        asm volatile("s_waitcnt vmcnt(8)" ::: "memory");
      } else {
        asm volatile("s_waitcnt vmcnt(0)" ::: "memory");
      }
      __builtin_amdgcn_s_barrier();
      asm volatile("" ::: "memory");

      // ---- QK^T (swapped): s0/s1[reg] = S[q=c][key g*8+reg (+4)] ----
      const char* kb = smem + cur * 32768;
      vf4 s0 = (vf4){0.f,0.f,0.f,0.f}, s1 = (vf4){0.f,0.f,0.f,0.f};
      #pragma unroll
      for (int ch = 0; ch < 16; ++ch){
        const char* pa = kb + kb_lane + ((ch ^ chx) << 6);
        vbf8 ka  = *(const vbf8*)(pa);
        vbf8 ka1 = *(const vbf8*)(pa + 4096);       // key+4 rows, same swizzle
        s0 = MFMA(ka,  qf[ch], s0);
        s1 = MFMA(ka1, qf[ch], s1);
      }
      // ---- exp + lane-local pack: pb = P[q=c][keys 8g..8g+7] ----
      float e00 = __expf(s0[0]), e01 = __expf(s0[1]), e02 = __expf(s0[2]), e03 = __expf(s0[3]);
      float e10 = __expf(s1[0]), e11 = __expf(s1[1]), e12 = __expf(s1[2]), e13 = __expf(s1[3]);
      lp += (e00 + e01 + e02 + e03) + (e10 + e11 + e12 + e13);
      vbf8 pb;
      pb[0]=(short)f2bf(e00); pb[1]=(short)f2bf(e01); pb[2]=(short)f2bf(e02); pb[3]=(short)f2bf(e03);
      pb[4]=(short)f2bf(e10); pb[5]=(short)f2bf(e11); pb[6]=(short)f2bf(e12); pb[7]=(short)f2bf(e13);
      // ---- PV: acc[ch] += Vt[d=ch*16+c][32 keys] * pb ----
      const char* vb = smem + 65536 + cur * 32768;
      #pragma unroll
      for (int ch = 0; ch < 32; ++ch){
        vbf8 va = *(const vbf8*)(vb + vb_lane + ch * 1024);
        acc[ch] = MFMA(va, pb, acc[ch]);
      }
      asm volatile("" ::: "memory");
      __builtin_amdgcn_s_barrier();                 // all waves done with buf[cur]
      asm volatile("" ::: "memory");
    }

    // ---- finalize source: denominator over 4 g-groups; merge into d_out ----
    float t = lp;
    t += __shfl_xor(t, 16);
    t += __shfl_xor(t, 32);
    const float w = 1.0f / t;
    lp = 0.f;
    float* op = outF + (size_t)(qbase + c) * 512 + g * 4;
    #pragma unroll
    for (int ch = 0; ch < 32; ++ch){
      float4* p4 = (float4*)(op + ch * 16);
      float4 v = *p4;
      v.x += acc[ch][0] * w; v.y += acc[ch][1] * w;
      v.z += acc[ch][2] * w; v.w += acc[ch][3] * w;
      if (srcI == 1){
        v.x = fmaxf(v.x, 0.f); v.y = fmaxf(v.y, 0.f);
        v.z = fmaxf(v.z, 0.f); v.w = fmaxf(v.w, 0.f);
      }
      *p4 = v;
      acc[ch] = (vf4){0.f, 0.f, 0.f, 0.f};
    }
  }
}

// ---------------- host launcher ----------------
extern "C" void kernel_launch(void* const* d_in, const int* in_sizes, int n_in,
                              void* d_out, int out_size, void* d_ws, size_t ws_size,
                              hipStream_t stream){
  const float* E0 = (const float*)d_in[0];
  const float* E1 = (const float*)d_in[1];
  const float* E2 = (const float*)d_in[2];
  const float* Wq = (const float*)d_in[3];
  const float* bq = (const float*)d_in[4];
  const float* Wk = (const float*)d_in[5];
  const float* bk = (const float*)d_in[6];
  const float* Wv = (const float*)d_in[7];
  const float* bv = (const float*)d_in[8];
  const float* Wo = (const float*)d_in[9];
  const float* bo = (const float*)d_in[10];
  float* outF = (float*)d_out;

  char* ws = (char*)d_ws;
  const size_t SZ = 75497472u;                 // 73728*512*2 bytes (bf16)
  u16* Wbf = (u16*)ws;                         // 2 MB
  u16* Qb  = (u16*)(ws + (size_t)(2u << 20));
  u16* Kb  = (u16*)(ws + (size_t)(2u << 20) + SZ);
  u16* Vtb = (u16*)(ws + (size_t)(2u << 20) + 2 * SZ);
  // requires ws_size >= 2MB + 3*72MB = ~228.6MB

  wconv_k<<<dim3(1024), dim3(256), 0, stream>>>(Wq, Wk, Wv, Wo, Wbf);
  proj_k<<<dim3(512, 4, 3), dim3(256), 0, stream>>>(E0, E1, E2, Wbf, bq, bk, bv, bo,
                                                    Qb, Kb, Vtb, outF);
  attn_k<<<dim3(576), dim3(512), 0, stream>>>(Qb, Kb, Vtb, outF);
}

// Round 6
// 941.321 us; speedup vs baseline: 4.8748x; 1.2163x over previous
//
#include <hip/hip_runtime.h>

// CrossModalHyperedgeInteraction: 3-modality cross-attention, MI355X bf16-MFMA impl.
// R6: proj_k rebuilt as ONE unified GEMM C[73728x2048] = E * [Wq|Wk|Wv|Wo]^T with
// per-N-tile epilogue; 128x128 tile, BK=64, dbuf LDS, gll16 B-staging, reg-staged A
// (fp32->bf16), XOR swizzle, XCD-chunked block order. attn_k/wconv_k unchanged from R5.
// D=512, B=32, K={1024,768,512}, tokOff={0,32768,57344}, total tokens 73728.

typedef unsigned short u16;
typedef unsigned int   u32;
typedef __attribute__((ext_vector_type(8))) short vbf8;   // 8 bf16 (4 VGPR) MFMA A/B frag
typedef __attribute__((ext_vector_type(4))) float vf4;    // MFMA C/D frag

#define MFMA(a,b,c) __builtin_amdgcn_mfma_f32_16x16x32_bf16(a,b,c,0,0,0)

__device__ __forceinline__ u16 f2bf(float f){
  u32 x = __float_as_uint(f);
  return (u16)((x + 0x7fffu + ((x >> 16) & 1u)) >> 16);   // RNE bf16
}

__device__ __forceinline__ void gll16(const void* g, void* l){
  __builtin_amdgcn_global_load_lds(
      (const __attribute__((address_space(1))) u32*)g,
      (__attribute__((address_space(3))) u32*)l, 16, 0, 0);
}

// ---------------- kernel 1: W fp32 -> bf16 (4 weights -> Wbf[2048][512]) ----------------
__global__ void wconv_k(const float* __restrict__ Wq, const float* __restrict__ Wk,
                        const float* __restrict__ Wv, const float* __restrict__ Wo,
                        u16* __restrict__ Wbf){
  int i = blockIdx.x * 256 + threadIdx.x;            // 0..262143, 4 floats each
  int w = i >> 16;
  int off = (i & 65535) << 2;
  const float* src = (w == 0) ? Wq : (w == 1) ? Wk : (w == 2) ? Wv : Wo;
  float4 v = *(const float4*)(src + off);
  u32 lo = (u32)f2bf(v.x) | ((u32)f2bf(v.y) << 16);
  u32 hi = (u32)f2bf(v.z) | ((u32)f2bf(v.w) << 16);
  uint2 p; p.x = lo; p.y = hi;
  *(uint2*)(Wbf + (w << 18) + off) = p;
}

// ---------------- kernel 2: unified projection GEMM ----------------
// 9216 blocks (576 M-tiles x 16 N-tiles), 256 thr (4 waves, 64x64 each).
// Per K-step(64): B tile via gll16 (linear LDS, pre-swizzled src), A tile reg-staged
// fp32->bf16 (issue-early / write-late), 1 barrier per step. Epilogue by widx = nt>>2:
// 0 -> Qb (x 1/sqrt(512)), 1 -> Kb, 2 -> Vt (LDS transpose), 3 -> O fp32 into d_out.
__global__ void __launch_bounds__(256, 2) proj_k(
    const float* __restrict__ E0, const float* __restrict__ E1, const float* __restrict__ E2,
    const u16* __restrict__ Wbf,
    const float* __restrict__ bq, const float* __restrict__ bk,
    const float* __restrict__ bv, const float* __restrict__ bo,
    u16* __restrict__ Qb, u16* __restrict__ Kb, u16* __restrict__ Vtb,
    float* __restrict__ outF)
{
  __shared__ __align__(16) char smem[65536];   // A dbuf 2x16KB @0 | B dbuf 2x16KB @32768

  const int lin = blockIdx.x;
  const int swz = (lin & 7) * 1152 + (lin >> 3);     // XCD-chunked (9216 = 8*1152)
  const int mt = swz >> 4, nt = swz & 15;
  const int widx = nt >> 2, colBase = (nt & 3) * 128;
  const int t0 = mt * 128;
  const int mod = (t0 >= 57344) ? 2 : (t0 >= 32768) ? 1 : 0;
  const int tokOffM = (mod == 0) ? 0 : (mod == 1) ? 32768 : 57344;
  const int Km = (mod == 0) ? 1024 : (mod == 1) ? 768 : 512;
  const float* E = (mod == 0) ? E0 : (mod == 1) ? E1 : E2;
  const float* bias = (widx == 0) ? bq : (widx == 1) ? bk : (widx == 2) ? bv : bo;

  const int tid = threadIdx.x, wv = tid >> 6, l = tid & 63, g = l >> 4, c = l & 15;
  const int wm = wv >> 1, wn = wv & 1;

  float4 ar[4][2];                                   // A-stage regs (fp32, 8 floats/unit)

  vf4 acc[4][4];
  #pragma unroll
  for (int mi = 0; mi < 4; ++mi)
    #pragma unroll
    for (int ni = 0; ni < 4; ++ni) acc[mi][ni] = (vf4){0.f, 0.f, 0.f, 0.f};

  auto loadA = [&](int kt){                          // issue fp32 E loads (pre-swizzled src)
    #pragma unroll
    for (int p = 0; p < 4; ++p){
      int t = p * 256 + tid, row = t >> 3, sl = t & 7;
      const float* s = E + (size_t)(t0 - tokOffM + row) * 512 + kt * 64 + ((sl ^ (row & 7)) << 3);
      ar[p][0] = *(const float4*)s;
      ar[p][1] = *(const float4*)(s + 4);
    }
  };
  auto glB = [&](int kt, int nxt){                   // B tile via global_load_lds
    char* dst = smem + 32768 + nxt * 16384;
    #pragma unroll
    for (int p = 0; p < 4; ++p){
      int t = p * 256 + tid, row = t >> 3, sl = t & 7;
      gll16(Wbf + (size_t)(nt * 128 + row) * 512 + kt * 64 + ((sl ^ (row & 7)) << 3),
            dst + t * 16);
    }
  };
  auto writeA = [&](int nxt){                        // convert + ds_write A tile
    char* dst = smem + nxt * 16384;
    #pragma unroll
    for (int p = 0; p < 4; ++p){
      int t = p * 256 + tid;
      int4 pk;
      pk.x = (int)((u32)f2bf(ar[p][0].x) | ((u32)f2bf(ar[p][0].y) << 16));
      pk.y = (int)((u32)f2bf(ar[p][0].z) | ((u32)f2bf(ar[p][0].w) << 16));
      pk.z = (int)((u32)f2bf(ar[p][1].x) | ((u32)f2bf(ar[p][1].y) << 16));
      pk.w = (int)((u32)f2bf(ar[p][1].z) | ((u32)f2bf(ar[p][1].w) << 16));
      *(int4*)(dst + t * 16) = pk;
    }
  };

  // prologue: stage k-step 0
  loadA(0); glB(0, 0);
  asm volatile("s_waitcnt vmcnt(0)" ::: "memory");
  writeA(0);
  __syncthreads();

  for (int kt = 0; kt < 8; ++kt){
    const int cur = kt & 1;
    if (kt < 7){ loadA(kt + 1); glB(kt + 1, cur ^ 1); }   // prefetch in flight over compute

    const char* A  = smem + cur * 16384;
    const char* Bl = smem + 32768 + cur * 16384;
    #pragma unroll
    for (int kh = 0; kh < 2; ++kh){
      vbf8 af[4], bf[4];
      #pragma unroll
      for (int mi = 0; mi < 4; ++mi){
        int row = wm * 64 + mi * 16 + c;
        af[mi] = *(const vbf8*)(A + row * 128 + ((((kh << 2) + g) ^ (row & 7)) << 4));
      }
      #pragma unroll
      for (int ni = 0; ni < 4; ++ni){
        int row = wn * 64 + ni * 16 + c;
        bf[ni] = *(const vbf8*)(Bl + row * 128 + ((((kh << 2) + g) ^ (row & 7)) << 4));
      }
      #pragma unroll
      for (int mi = 0; mi < 4; ++mi)
        #pragma unroll
        for (int ni = 0; ni < 4; ++ni)
          acc[mi][ni] = MFMA(af[mi], bf[ni], acc[mi][ni]);
    }

    asm volatile("s_waitcnt vmcnt(0)" ::: "memory");      // drain gll + A-reg loads
    if (kt < 7) writeA(cur ^ 1);
    __syncthreads();                                      // buf[cur^1] staged; buf[cur] free
  }

  // ---------------- epilogue ----------------
  if (widx == 2){
    // V: transpose via LDS T[128 e][136] (reuses staging LDS; all compute done at barrier)
    u16* T = (u16*)smem;
    #pragma unroll
    for (int ni = 0; ni < 4; ++ni){
      int el = wn * 64 + ni * 16 + c;
      float bb = bias[colBase + el];
      #pragma unroll
      for (int mi = 0; mi < 4; ++mi)
        #pragma unroll
        for (int r = 0; r < 4; ++r){
          int tk = wm * 64 + mi * 16 + g * 4 + r;
          T[el * 136 + tk] = f2bf(acc[mi][ni][r] + bb);
        }
    }
    __syncthreads();
    const int b = (t0 - tokOffM) / Km, tokl = (t0 - tokOffM) - b * Km;
    const size_t vbase = (size_t)tokOffM * 512 + (size_t)b * 512 * Km + tokl;
    #pragma unroll
    for (int it = 0; it < 8; ++it){
      int flat = it * 256 + tid;
      int el = flat >> 4, tg = flat & 15;
      const u16* tp = T + el * 136 + tg * 8;
      int4 pk;
      pk.x = (int)((u32)tp[0] | ((u32)tp[1] << 16));
      pk.y = (int)((u32)tp[2] | ((u32)tp[3] << 16));
      pk.z = (int)((u32)tp[4] | ((u32)tp[5] << 16));
      pk.w = (int)((u32)tp[6] | ((u32)tp[7] << 16));
      *(int4*)(Vtb + vbase + (size_t)(colBase + el) * Km + tg * 8) = pk;
    }
  } else {
    const float scale = (widx == 0) ? 0.04419417382415922f : 1.0f;   // 1/sqrt(512) into Q
    #pragma unroll
    for (int ni = 0; ni < 4; ++ni){
      int col = colBase + wn * 64 + ni * 16 + c;
      float bb = bias[col];
      #pragma unroll
      for (int mi = 0; mi < 4; ++mi)
        #pragma unroll
        for (int r = 0; r < 4; ++r){
          int token = t0 + wm * 64 + mi * 16 + g * 4 + r;
          float val = (acc[mi][ni][r] + bb) * scale;
          size_t idx = (size_t)token * 512 + col;
          if (widx == 3)      outF[idx] = val;            // O proj fp32 (relu in attn)
          else if (widx == 0) Qb[idx] = f2bf(val);
          else                Kb[idx] = f2bf(val);
        }
    }
  }
}

// ---------------- kernel 3: cross attention (async dbuf LDS pipeline, = R5) ----------------
__global__ void __launch_bounds__(512, 2) attn_k(
    const u16* __restrict__ Qb, const u16* __restrict__ Kb,
    const u16* __restrict__ Vtb, float* __restrict__ outF)
{
  __shared__ __align__(16) char smem[131072];  // K dbuf 2x32KB @0 | Vt dbuf 2x32KB @65536

  const int lin = blockIdx.x;
  const int swz = (lin & 7) * 72 + (lin >> 3);
  int m, y, xq;
  if (swz < 256)      { m = 0; y = swz >> 3; xq = swz & 7; }
  else if (swz < 448) { int r = swz - 256; m = 1; y = r / 6; xq = r - y * 6; }
  else                { int r = swz - 448; m = 2; y = r >> 2; xq = r & 3; }

  const int Km = (m == 0) ? 1024 : (m == 1) ? 768 : 512;
  const int tokOffM = (m == 0) ? 0 : (m == 1) ? 32768 : 57344;

  const int tid = threadIdx.x, wv = tid >> 6, l = tid & 63, g = l >> 4, c = l & 15;
  const int qbase = tokOffM + y * Km + xq * 128 + wv * 16;

  const int kperm = (c >> 2) * 8 + (c & 3);        // A-row -> key permutation (sel 0)
  const int chx   = c >> 2;                        // K-read slot XOR (high bits of F)
  const int kb_lane = kperm * 1024 + ((g ^ (c & 3)) << 4);
  const int vb_lane = c * 64 + ((g ^ ((c >> 1) & 3)) << 4);

  vbf8 qf[16];
  {
    const u16* qp = Qb + (size_t)(qbase + c) * 512 + g * 8;
    #pragma unroll
    for (int ch = 0; ch < 16; ++ch) qf[ch] = *(const vbf8*)(qp + ch * 32);
  }

  vf4 acc[32];
  #pragma unroll
  for (int ch = 0; ch < 32; ++ch) acc[ch] = (vf4){0.f, 0.f, 0.f, 0.f};
  float lp = 0.f;

  for (int srcI = 0; srcI < 2; ++srcI){
    const int n = (srcI == 0) ? ((m == 0) ? 1 : 0) : ((m == 2) ? 1 : 2);
    const int Kn = (n == 0) ? 1024 : (n == 1) ? 768 : 512;
    const int NT = Kn >> 5;
    const int tokOffN = (n == 0) ? 0 : (n == 1) ? 32768 : 57344;
    const size_t kRow0 = (size_t)(tokOffN + y * Kn);
    const size_t vBase = (size_t)tokOffN * 512 + (size_t)y * 512 * Kn;

    auto stage = [&](int kt, int buf){
      char* kd = smem + buf * 32768;
      char* vd = smem + 65536 + buf * 32768;
      const size_t kB = (kRow0 + kt * 32) * 512;
      #pragma unroll
      for (int p = 0; p < 4; ++p){                  // K tile: linear LDS, pre-swizzled src
        int t = p * 512 + tid;
        int key = t >> 6, sl = t & 63;
        int F = (key & 3) | (((key >> 3) & 3) << 2);
        gll16(Kb + kB + (size_t)key * 512 + ((sl ^ F) << 3), kd + t * 16);
      }
      #pragma unroll
      for (int p = 0; p < 4; ++p){                  // Vt tile
        int t = p * 512 + tid;
        int d = t >> 2, ks = t & 3;
        gll16(Vtb + vBase + (size_t)d * Kn + kt * 32 + ((ks ^ ((d >> 1) & 3)) << 3),
              vd + t * 16);
      }
    };

    stage(0, 0);
    for (int kt = 0; kt < NT; ++kt){
      const int cur = kt & 1;
      if (kt + 1 < NT){
        stage(kt + 1, cur ^ 1);                     // prefetch stays in flight
        asm volatile("s_waitcnt vmcnt(8)" ::: "memory");
      } else {
        asm volatile("s_waitcnt vmcnt(0)" ::: "memory");
      }
      __builtin_amdgcn_s_barrier();
      asm volatile("" ::: "memory");

      const char* kb = smem + cur * 32768;
      vf4 s0 = (vf4){0.f,0.f,0.f,0.f}, s1 = (vf4){0.f,0.f,0.f,0.f};
      #pragma unroll
      for (int ch = 0; ch < 16; ++ch){
        const char* pa = kb + kb_lane + ((ch ^ chx) << 6);
        vbf8 ka  = *(const vbf8*)(pa);
        vbf8 ka1 = *(const vbf8*)(pa + 4096);       // key+4 rows, same swizzle
        s0 = MFMA(ka,  qf[ch], s0);
        s1 = MFMA(ka1, qf[ch], s1);
      }
      float e00 = __expf(s0[0]), e01 = __expf(s0[1]), e02 = __expf(s0[2]), e03 = __expf(s0[3]);
      float e10 = __expf(s1[0]), e11 = __expf(s1[1]), e12 = __expf(s1[2]), e13 = __expf(s1[3]);
      lp += (e00 + e01 + e02 + e03) + (e10 + e11 + e12 + e13);
      vbf8 pb;
      pb[0]=(short)f2bf(e00); pb[1]=(short)f2bf(e01); pb[2]=(short)f2bf(e02); pb[3]=(short)f2bf(e03);
      pb[4]=(short)f2bf(e10); pb[5]=(short)f2bf(e11); pb[6]=(short)f2bf(e12); pb[7]=(short)f2bf(e13);
      const char* vb = smem + 65536 + cur * 32768;
      #pragma unroll
      for (int ch = 0; ch < 32; ++ch){
        vbf8 va = *(const vbf8*)(vb + vb_lane + ch * 1024);
        acc[ch] = MFMA(va, pb, acc[ch]);
      }
      asm volatile("" ::: "memory");
      __builtin_amdgcn_s_barrier();                 // all waves done with buf[cur]
      asm volatile("" ::: "memory");
    }

    float t = lp;
    t += __shfl_xor(t, 16);
    t += __shfl_xor(t, 32);
    const float w = 1.0f / t;
    lp = 0.f;
    float* op = outF + (size_t)(qbase + c) * 512 + g * 4;
    #pragma unroll
    for (int ch = 0; ch < 32; ++ch){
      float4* p4 = (float4*)(op + ch * 16);
      float4 v = *p4;
      v.x += acc[ch][0] * w; v.y += acc[ch][1] * w;
      v.z += acc[ch][2] * w; v.w += acc[ch][3] * w;
      if (srcI == 1){
        v.x = fmaxf(v.x, 0.f); v.y = fmaxf(v.y, 0.f);
        v.z = fmaxf(v.z, 0.f); v.w = fmaxf(v.w, 0.f);
      }
      *p4 = v;
      acc[ch] = (vf4){0.f, 0.f, 0.f, 0.f};
    }
  }
}

// ---------------- host launcher ----------------
extern "C" void kernel_launch(void* const* d_in, const int* in_sizes, int n_in,
                              void* d_out, int out_size, void* d_ws, size_t ws_size,
                              hipStream_t stream){
  const float* E0 = (const float*)d_in[0];
  const float* E1 = (const float*)d_in[1];
  const float* E2 = (const float*)d_in[2];
  const float* Wq = (const float*)d_in[3];
  const float* bq = (const float*)d_in[4];
  const float* Wk = (const float*)d_in[5];
  const float* bk = (const float*)d_in[6];
  const float* Wv = (const float*)d_in[7];
  const float* bv = (const float*)d_in[8];
  const float* Wo = (const float*)d_in[9];
  const float* bo = (const float*)d_in[10];
  float* outF = (float*)d_out;

  char* ws = (char*)d_ws;
  const size_t SZ = 75497472u;                 // 73728*512*2 bytes (bf16)
  u16* Wbf = (u16*)ws;                         // 2 MB, laid out as [2048][512]
  u16* Qb  = (u16*)(ws + (size_t)(2u << 20));
  u16* Kb  = (u16*)(ws + (size_t)(2u << 20) + SZ);
  u16* Vtb = (u16*)(ws + (size_t)(2u << 20) + 2 * SZ);
  // requires ws_size >= 2MB + 3*72MB = ~228.6MB

  wconv_k<<<dim3(1024), dim3(256), 0, stream>>>(Wq, Wk, Wv, Wo, Wbf);
  proj_k<<<dim3(9216), dim3(256), 0, stream>>>(E0, E1, E2, Wbf, bq, bk, bv, bo,
                                               Qb, Kb, Vtb, outF);
  attn_k<<<dim3(576), dim3(512), 0, stream>>>(Qb, Kb, Vtb, outF);
}